// Round 5
// baseline (53106.281 us; speedup 1.0000x reference)
//
#include <hip/hip_runtime.h>
#include <hip/hip_bf16.h>
#include <math.h>

// ---------------- problem constants ----------------
#define B_    8
#define D_    256
#define NH_   4
#define N_    4096
#define T_    197
#define NL_   6
#define NCLS_ 1000
#define EPSV  1e-5f
#define HALF_N 2048
#define BT_   (B_*T_)        // 1576
#define BH_   (B_*NH_)       // 32
#define BHT_  (B_*NH_*T_)    // 6304
#define TN_   (T_*N_)        // 806912

// Working hypothesis (round 5): inputs fp32 (confirmed), OUTPUT fp32 (new).
typedef float out_t;
__device__ __forceinline__ out_t STOUT(float v){ return v; }

// ---------------- helpers ----------------
__device__ __forceinline__ float blockSum256(float v, float* s4){
  #pragma unroll
  for (int o = 32; o > 0; o >>= 1) v += __shfl_down(v, o, 64);
  __syncthreads();
  if ((threadIdx.x & 63) == 0) s4[threadIdx.x >> 6] = v;
  __syncthreads();
  return s4[0] + s4[1] + s4[2] + s4[3];
}

// ---------------- K0: rope tables ----------------
__global__ void k_tables(float* cosT, float* sinT){
  int t = blockIdx.x;
  for (int k = threadIdx.x; k < HALF_N; k += blockDim.x){
    float f32 = (float)exp2(-(double)k / 128.0);   // THETA^(-2k/N), fp32-rounded
    float ph32 = (float)t * f32;                   // fp32 phase like the reference
    double s, c;
    sincos((double)ph32, &s, &c);
    cosT[t*HALF_N + k] = (float)c;
    sinT[t*HALF_N + k] = (float)s;
  }
}

// ---------------- K1: patch embed + pos + LN -> h (naive) ----------------
__global__ void k_embed(const float* x, const float* pw, const float* pb,
                        const float* cls, const float* pos, float* h){
  __shared__ float s4[4];
  int b = blockIdx.x / T_;
  int t = blockIdx.x % T_;
  int d = threadIdx.x;
  float val;
  if (t == 0){
    val = cls[d];
  } else {
    int g = t - 1, gy = g / 14, gx = g % 14;
    float acc = pb[d];
    const float* wrow = pw + (size_t)d*768;
    for (int c = 0; c < 3; c++)
      for (int r = 0; r < 16; r++)
        for (int q = 0; q < 16; q++)
          acc = fmaf(x[((size_t)(b*3 + c)*224 + (gy*16 + r))*224 + (gx*16 + q)],
                     wrow[c*256 + r*16 + q], acc);
    val = acc;
  }
  val += pos[(size_t)t*D_ + d];
  float m  = blockSum256(val, s4) * (1.f/256.f);
  float dv = val - m;
  float vr = blockSum256(dv*dv, s4) * (1.f/256.f);
  h[((size_t)b*T_ + t)*D_ + d] = dv * rsqrtf(vr + EPSV);
}

// ---------------- K2/K5: naive encoder GEMM, one thread per (bh,t,n) ----------------
template<int MODE>
__global__ void k_enc(const float* Abase, const float* W, float* xs){
  int idx = blockIdx.x*256 + threadIdx.x;
  int bh  = idx / TN_;
  int rem = idx - bh*TN_;
  int t   = rem >> 12;
  int n   = rem & (N_-1);
  int b = bh >> 2, hh = bh & 3;
  const float* A = (MODE == 0) ? Abase + ((size_t)b*T_ + t)*D_
                               : Abase + ((size_t)bh*T_ + t)*D_;
  const float* w = W + (size_t)hh*D_*N_ + n;
  float acc = 0.f;
  for (int d = 0; d < D_; d++) acc = fmaf(A[d], w[(size_t)d*N_], acc);
  acc = acc > 0.f ? acc : 0.f;
  if (MODE == 1) acc *= xs[idx];
  xs[idx] = acc;
}

// ---------------- K3: naive scores, one thread per (t,s) ----------------
__global__ void k_scores(const float* xs, const float* cosT, const float* sinT, float* sc){
  int t  = blockIdx.x;
  int bh = blockIdx.y;
  int s  = threadIdx.x;
  if (s >= T_) return;
  float acc = 0.f;
  if (s < t){
    const float* Xt = xs + (size_t)bh*TN_ + (size_t)t*N_;
    const float* Xs = xs + (size_t)bh*TN_ + (size_t)s*N_;
    const float* Ct = cosT + (size_t)t*HALF_N;
    const float* St = sinT + (size_t)t*HALF_N;
    const float* Cs = cosT + (size_t)s*HALF_N;
    const float* Ss = sinT + (size_t)s*HALF_N;
    for (int i = 0; i < HALF_N; i++){
      float a0 = Xt[2*i], a1 = Xt[2*i+1];
      float b0 = Xs[2*i], b1 = Xs[2*i+1];
      float ct = Ct[i], st = St[i], cs = Cs[i], ss = Ss[i];
      float qa0 = a0*ct - a1*st;
      float qa1 = fmaf(a1, ct, a0*st);
      float qb0 = b0*cs - b1*ss;
      float qb1 = fmaf(b1, cs, b0*ss);
      acc += qa0*qb0 + qa1*qb1;
    }
  }
  sc[((size_t)bh*T_ + t)*T_ + s] = acc;
}

// ---------------- K4: yKV = ln(scores @ h) ----------------
__global__ void k_ykv(const float* sc, const float* h, float* yKV){
  __shared__ float srow[256];
  __shared__ float s4[4];
  int bht = blockIdx.x;
  int bh = bht / T_, t = bht % T_;
  int b = bh >> 2;
  int d = threadIdx.x;
  if (d < T_) srow[d] = sc[(size_t)bht*T_ + d];
  __syncthreads();
  float acc = 0.f;
  const float* hb = h + (size_t)b*T_*D_;
  for (int s = 0; s < t; s++) acc = fmaf(srow[s], hb[(size_t)s*D_ + d], acc);
  float m  = blockSum256(acc, s4) * (1.f/256.f);
  float dv = acc - m;
  float vr = blockSum256(dv*dv, s4) * (1.f/256.f);
  yKV[(size_t)bht*D_ + d] = dv * rsqrtf(vr + EPSV);
}

// ---------------- K6: naive decoder GEMM ----------------
__global__ void k_dec(const float* xs, const float* dec, float* yML){
  int idx = blockIdx.x*256 + threadIdx.x;
  int d   = idx & (D_-1);
  int bht = idx >> 8;
  int bh  = bht / T_;
  int hh  = bh & 3;
  const float* A = xs + (size_t)bht*N_;
  const float* w = dec + (size_t)hh*N_*D_ + d;
  float acc = 0.f;
  for (int n = 0; n < N_; n++) acc = fmaf(A[n], w[(size_t)n*D_], acc);
  yML[idx] = acc;
}

// ---------------- K7: h = ln(h + ln(sum_h yML)) ----------------
__global__ void k_hupdate(const float* yML, float* h){
  __shared__ float s4[4];
  int bt = blockIdx.x;
  int b = bt / T_, t = bt % T_;
  int d = threadIdx.x;
  float y = 0.f;
  #pragma unroll
  for (int hh = 0; hh < NH_; hh++)
    y += yML[(((size_t)(b*NH_ + hh))*T_ + t)*D_ + d];
  float m  = blockSum256(y, s4) * (1.f/256.f);
  float dv = y - m;
  float vr = blockSum256(dv*dv, s4) * (1.f/256.f);
  float u  = h[(size_t)bt*D_ + d] + dv * rsqrtf(vr + EPSV);
  float m2  = blockSum256(u, s4) * (1.f/256.f);
  float dv2 = u - m2;
  float vr2 = blockSum256(dv2*dv2, s4) * (1.f/256.f);
  h[(size_t)bt*D_ + d] = dv2 * rsqrtf(vr2 + EPSV);
}

// ---------------- K8: head ----------------
__global__ void k_head(const float* h, const float* hg, const float* hb,
                       const float* hw, const float* hbias, out_t* out){
  __shared__ float cn[256];
  __shared__ float s4[4];
  int b = blockIdx.x, d = threadIdx.x;
  float v = h[(size_t)b*T_*D_ + d];
  float m  = blockSum256(v, s4) * (1.f/256.f);
  float dv = v - m;
  float vr = blockSum256(dv*dv, s4) * (1.f/256.f);
  cn[d] = dv * rsqrtf(vr + EPSV) * hg[d] + hb[d];
  __syncthreads();
  for (int j = d; j < NCLS_; j += 256){
    float acc = hbias[j];
    for (int k = 0; k < 256; k++) acc = fmaf(cn[k], hw[(size_t)k*NCLS_ + j], acc);
    out[(size_t)b*NCLS_ + j] = STOUT(acc);
  }
}

// ---------------- sentinel ----------------
__global__ void k_sentinel(out_t* out, float code){
  int i = blockIdx.x*256 + threadIdx.x;
  if (i < B_*NCLS_) out[i] = STOUT(code);
}

// ---------------- launch ----------------
extern "C" void kernel_launch(void* const* d_in, const int* in_sizes, int n_in,
                              void* d_out, int out_size, void* d_ws, size_t ws_size,
                              hipStream_t stream) {
  out_t* out = (out_t*)d_out;

  static const int EXP_SIZES[12] = {
    1204224, 196608, 256, 256, 50432,
    4194304, 4194304, 4194304, 256, 256, 256000, 1000
  };
  if (n_in != 12){
    k_sentinel<<<(B_*NCLS_ + 255)/256, 256, 0, stream>>>(out, 1000.f + n_in);
    return;
  }
  for (int i = 0; i < 12; i++){
    if (in_sizes[i] != EXP_SIZES[i]){
      k_sentinel<<<(B_*NCLS_ + 255)/256, 256, 0, stream>>>(out, 2000.f + 100.f*i);
      return;
    }
  }

  const float* x     = (const float*)d_in[0];
  const float* pw    = (const float*)d_in[1];
  const float* pb    = (const float*)d_in[2];
  const float* cls   = (const float*)d_in[3];
  const float* pos   = (const float*)d_in[4];
  const float* enc   = (const float*)d_in[5];
  const float* encv  = (const float*)d_in[6];
  const float* dec   = (const float*)d_in[7];
  const float* hg    = (const float*)d_in[8];
  const float* hbv   = (const float*)d_in[9];
  const float* hw    = (const float*)d_in[10];
  const float* hbias = (const float*)d_in[11];

  size_t oCos = 0;
  size_t oSin = oCos + (size_t)T_*HALF_N;
  size_t oH   = oSin + (size_t)T_*HALF_N;
  size_t oXS  = oH   + (size_t)BT_*D_;
  size_t oSC  = oXS  + (size_t)BHT_*N_;
  size_t oYKV = oSC  + (size_t)BH_*T_*T_;
  size_t oYML = oYKV + (size_t)BHT_*D_;
  size_t needF = oYML + (size_t)BHT_*D_;
  if (ws_size < needF*sizeof(float)) {
    k_sentinel<<<(B_*NCLS_ + 255)/256, 256, 0, stream>>>(out, 9000.f);
    return;
  }
  float* ws   = (float*)d_ws;
  float* cosT = ws + oCos;
  float* sinT = ws + oSin;
  float* h    = ws + oH;
  float* xs   = ws + oXS;
  float* sc   = ws + oSC;
  float* yKV  = ws + oYKV;
  float* yML  = ws + oYML;

  k_tables<<<T_, 256, 0, stream>>>(cosT, sinT);
  k_embed <<<BT_, 256, 0, stream>>>(x, pw, pb, cls, pos, h);

  for (int l = 0; l < NL_; l++){
    k_enc<0><<<(BHT_*(size_t)N_)/256, 256, 0, stream>>>(h, enc, xs);
    k_scores <<<dim3(T_, BH_), 256, 0, stream>>>(xs, cosT, sinT, sc);
    k_ykv    <<<BHT_, 256, 0, stream>>>(sc, h, yKV);
    k_enc<1><<<(BHT_*(size_t)N_)/256, 256, 0, stream>>>(yKV, encv, xs);
    k_dec    <<<(BHT_*(size_t)D_)/256, 256, 0, stream>>>(xs, dec, yML);
    k_hupdate<<<BT_, 256, 0, stream>>>(yML, h);
  }
  k_head<<<B_, 256, 0, stream>>>(h, hg, hbv, hw, hbias, out);
}

// Round 6
// 34.118 us; speedup vs baseline: 1556.5562x; 1556.5562x over previous
//
#include <hip/hip_runtime.h>
#include <hip/hip_bf16.h>
#include <math.h>

// ---------------- problem constants ----------------
#define B_    8
#define D_    256
#define NCLS_ 1000
#define EPSV  1e-5f

// Confirmed round 5: inputs fp32, OUTPUT fp32 (comparison happens in bf16 space,
// which is why earlier bf16-buffer writes scored exactly 1.66 = decorrelated).
typedef float out_t;

// STRUCTURAL FACT (verified analytically; consistent with round-5 full-pipeline pass):
//   mask = tril(ones(T,T), k=-1)  =>  scores[b,h,0,:] == 0 (token 0 attends to nothing)
//   => yKV[b,h,0,:] = ln(0) = 0
//   => y_sparse[t=0] = relu(0 @ encoder_v) = 0
//   => xy_sparse[t=0] = x_sparse[t=0] * 0 = 0
//   => yMLP[b,0,:] = 0  =>  ln(yMLP)[b,0,:] = 0
//   => per layer: h[:,0] <- ln(h[:,0] + 0) = ln(h[:,0])
//   head reads ONLY h[:,0]  =>
//   out[b,:] = ( LN_affine( ln^7(cls_token + pos_emb[0,0,:]) ) ) @ head_w + head_bias
//   (identical for every b). The 6-layer network is dead code for the output.

__device__ __forceinline__ float blockSum256(float v, float* s4){
  #pragma unroll
  for (int o = 32; o > 0; o >>= 1) v += __shfl_down(v, o, 64);
  __syncthreads();
  if ((threadIdx.x & 63) == 0) s4[threadIdx.x >> 6] = v;
  __syncthreads();
  return s4[0] + s4[1] + s4[2] + s4[3];
}

__global__ void k_cls(const float* __restrict__ cls, const float* __restrict__ pos,
                      const float* __restrict__ hg,  const float* __restrict__ hb,
                      const float* __restrict__ hw,  const float* __restrict__ hbias,
                      out_t* __restrict__ out){
  __shared__ float cn[256];
  __shared__ float s4[4];
  int b = blockIdx.x;
  int d = threadIdx.x;
  float v = cls[d] + pos[d];            // seq[b,0,:] = cls_token + pos_emb[0,0,:]
  // h = ln(seq), then 6 layers of h = ln(h + ln(0)) = ln(h)   -> 7 plain LNs
  #pragma unroll 1
  for (int i = 0; i < 7; i++){
    float m  = blockSum256(v, s4) * (1.f/256.f);
    float dv = v - m;
    float vr = blockSum256(dv*dv, s4) * (1.f/256.f);
    v = dv * rsqrtf(vr + EPSV);
    __syncthreads();
  }
  // head LN with affine
  float m  = blockSum256(v, s4) * (1.f/256.f);
  float dv = v - m;
  float vr = blockSum256(dv*dv, s4) * (1.f/256.f);
  cn[d] = dv * rsqrtf(vr + EPSV) * hg[d] + hb[d];
  __syncthreads();
  // logits = cn @ head_w + head_bias ; wave reads 64 consecutive j at fixed k (coalesced)
  for (int j = d; j < NCLS_; j += 256){
    float acc = hbias[j];
    #pragma unroll 8
    for (int k = 0; k < 256; k++) acc = fmaf(cn[k], hw[(size_t)k*NCLS_ + j], acc);
    out[(size_t)b*NCLS_ + j] = acc;
  }
}

// Diagnostic sentinel (decodable constant -> absmax identifies failure mode).
__global__ void k_sentinel(out_t* out, float code){
  int i = blockIdx.x*256 + threadIdx.x;
  if (i < B_*NCLS_) out[i] = code;
}

extern "C" void kernel_launch(void* const* d_in, const int* in_sizes, int n_in,
                              void* d_out, int out_size, void* d_ws, size_t ws_size,
                              hipStream_t stream) {
  out_t* out = (out_t*)d_out;

  static const int EXP_SIZES[12] = {
    1204224, 196608, 256, 256, 50432,
    4194304, 4194304, 4194304, 256, 256, 256000, 1000
  };
  if (n_in != 12){
    k_sentinel<<<(B_*NCLS_ + 255)/256, 256, 0, stream>>>(out, 1000.f + n_in);
    return;
  }
  for (int i = 0; i < 12; i++){
    if (in_sizes[i] != EXP_SIZES[i]){
      k_sentinel<<<(B_*NCLS_ + 255)/256, 256, 0, stream>>>(out, 2000.f + 100.f*i);
      return;
    }
  }

  const float* cls   = (const float*)d_in[3];
  const float* pos   = (const float*)d_in[4];   // row 0
  const float* hg    = (const float*)d_in[8];
  const float* hb    = (const float*)d_in[9];
  const float* hw    = (const float*)d_in[10];
  const float* hbias = (const float*)d_in[11];

  k_cls<<<B_, 256, 0, stream>>>(cls, pos, hg, hb, hw, hbias, out);
}

// Round 7
// 13.116 us; speedup vs baseline: 4048.9714x; 2.6012x over previous
//
#include <hip/hip_runtime.h>
#include <hip/hip_bf16.h>
#include <math.h>

// ---------------- problem constants ----------------
#define B_    8
#define D_    256
#define NCLS_ 1000
#define EPSV  1e-5f

typedef float out_t;  // confirmed: output buffer fp32 (checked in bf16 space)

// STRUCTURAL FACT (verified analytically + empirically round 5/6):
//   tril(k=-1) mask => token 0 attends to nothing => per layer h[:,0] <- ln(h[:,0]);
//   head reads only h[:,0] =>
//   out[b,:] = LN_affine( ln^7(cls_token + pos_emb[0,0,:]) ) @ head_w + head_bias,
//   identical for every b. The 6-layer network is dead code for the output.

// One kernel, grid (8 slices x 8 batch), 256 threads.
// Phase 1: every wave redundantly computes the 8-LN chain entirely in registers
//          (4 elems/lane, stride 64) with shfl_xor butterflies -- no barriers.
// Phase 2: 2 threads per logit (k split 0-127 / 128-255), partials via LDS.
__global__ void k_cls(const float* __restrict__ cls, const float* __restrict__ pos,
                      const float* __restrict__ hg,  const float* __restrict__ hb,
                      const float* __restrict__ hw,  const float* __restrict__ hbias,
                      out_t* __restrict__ out){
  __shared__ float cn[256];
  __shared__ float part[128];
  int slice = blockIdx.x;        // 0..7 -> logits [slice*128, slice*128+128)
  int b     = blockIdx.y;        // 0..7
  int tid   = threadIdx.x;
  int lane  = tid & 63;

  // ---- Phase 1: LN chain (wave-local, barrier-free) ----
  float x0 = cls[lane]       + pos[lane];
  float x1 = cls[lane + 64]  + pos[lane + 64];
  float x2 = cls[lane + 128] + pos[lane + 128];
  float x3 = cls[lane + 192] + pos[lane + 192];
  #pragma unroll 1
  for (int i = 0; i < 8; i++){          // embed-LN + 6 layer-LNs + head-LN core
    float s = x0 + x1 + x2 + x3;
    #pragma unroll
    for (int m = 32; m >= 1; m >>= 1) s += __shfl_xor(s, m, 64);
    float mean = s * (1.f/256.f);
    x0 -= mean; x1 -= mean; x2 -= mean; x3 -= mean;
    float q = x0*x0 + x1*x1 + x2*x2 + x3*x3;
    #pragma unroll
    for (int m = 32; m >= 1; m >>= 1) q += __shfl_xor(q, m, 64);
    float r = rsqrtf(q * (1.f/256.f) + EPSV);
    x0 *= r; x1 *= r; x2 *= r; x3 *= r;
  }
  if (tid < 64){                        // wave 0 publishes cn = x*hg + hb
    cn[lane]       = x0*hg[lane]       + hb[lane];
    cn[lane + 64]  = x1*hg[lane + 64]  + hb[lane + 64];
    cn[lane + 128] = x2*hg[lane + 128] + hb[lane + 128];
    cn[lane + 192] = x3*hg[lane + 192] + hb[lane + 192];
  }
  __syncthreads();

  // ---- Phase 2: logits = cn @ head_w + head_bias, 2 threads per j ----
  int jl = tid & 127, ty = tid >> 7;    // ty: k-half
  int j  = slice*128 + jl;
  float acc = 0.f;
  if (j < NCLS_){
    const float* w = hw + (size_t)(ty*128)*NCLS_ + j;   // coalesced across jl
    #pragma unroll 8
    for (int k = 0; k < 128; k++)
      acc = fmaf(cn[ty*128 + k], w[(size_t)k*NCLS_], acc);
  }
  if (ty == 1) part[jl] = acc;
  __syncthreads();
  if (ty == 0 && j < NCLS_)
    out[(size_t)b*NCLS_ + j] = acc + part[jl] + hbias[j];
}

// Diagnostic sentinel (decodable constant -> absmax identifies failure mode).
__global__ void k_sentinel(out_t* out, float code){
  int i = blockIdx.x*256 + threadIdx.x;
  if (i < B_*NCLS_) out[i] = code;
}

extern "C" void kernel_launch(void* const* d_in, const int* in_sizes, int n_in,
                              void* d_out, int out_size, void* d_ws, size_t ws_size,
                              hipStream_t stream) {
  out_t* out = (out_t*)d_out;

  static const int EXP_SIZES[12] = {
    1204224, 196608, 256, 256, 50432,
    4194304, 4194304, 4194304, 256, 256, 256000, 1000
  };
  if (n_in != 12){
    k_sentinel<<<(B_*NCLS_ + 255)/256, 256, 0, stream>>>(out, 1000.f + n_in);
    return;
  }
  for (int i = 0; i < 12; i++){
    if (in_sizes[i] != EXP_SIZES[i]){
      k_sentinel<<<(B_*NCLS_ + 255)/256, 256, 0, stream>>>(out, 2000.f + 100.f*i);
      return;
    }
  }

  const float* cls   = (const float*)d_in[3];
  const float* pos   = (const float*)d_in[4];   // row 0
  const float* hg    = (const float*)d_in[8];
  const float* hb    = (const float*)d_in[9];
  const float* hw    = (const float*)d_in[10];
  const float* hbias = (const float*)d_in[11];

  k_cls<<<dim3(8, B_), 256, 0, stream>>>(cls, pos, hg, hb, hw, hbias, out);
}